// Round 6
// baseline (82126.575 us; speedup 1.0000x reference)
//
#include <hip/hip_runtime.h>
#include <hip/hip_bf16.h>
#include <math.h>

// ---------------- problem constants ----------------
constexpr int NB  = 8;
constexpr int TT  = 4096;
constexpr int DD  = 256;
constexpr int CK  = 64;
constexpr int NCK = 64;
constexpr float ETA_SC = 1e-3f;
constexpr float EPSV   = 1e-6f;

constexpr size_t MSZ = (size_t)DD*DD;   // 65536

// ---------- fp32 region (element offsets into float* W) ----------
constexpr size_t OFF_W2  = 0;                               // [8][6][256*256]
constexpr size_t OFF_W1B = OFF_W2  + (size_t)NB*6*MSZ;      // [8][4][256*256]  (k,v,q,mem)
constexpr size_t OFF_W1S = OFF_W1B + (size_t)NB*4*MSZ;      // [8][2][256]
constexpr size_t OFF_WSK = OFF_W1S + (size_t)NB*2*DD;       // [8][2][256]
constexpr size_t OFF_SCK = OFF_WSK + (size_t)NB*2*DD;       // [8][64]
constexpr size_t OFF_SCQ = OFF_SCK + (size_t)NB*CK;         // [8][64]
constexpr size_t OFF_VSUM= OFF_SCQ + (size_t)NB*CK;         // [8][64]
constexpr size_t OFF_ETA = OFF_VSUM+ (size_t)NB*CK;         // [8][64]
constexpr size_t OFF_GS  = OFF_ETA + (size_t)NB*CK;         // [8][2][64]
constexpr size_t OFF_SALP= OFF_GS  + (size_t)NB*2*CK;       // [8][64] sigmoid(alpha)
constexpr size_t OFF_ABAR= OFF_SALP+ (size_t)NB*CK;         // [8]
constexpr size_t OFF_BARC= OFF_ABAR + NB;                   // [8] per-b barrier counters (uint)
constexpr size_t FTOT    = OFF_BARC + NB;

// ---------- bf16 region (element offsets into __hip_bfloat16* B) ----------
constexpr size_t BOFF_F  = 0;                               // [3][8][64][256]  F_k,F_v,F_q
constexpr size_t BOFF_H  = BOFF_F  + (size_t)3*NB*CK*DD;    // [8][6][64][256]  h=gelu(zu)
constexpr size_t BOFF_GB = BOFF_H  + (size_t)NB*6*CK*DD;    // [8][4][64][256]  g (big mems)
constexpr size_t BOFF_P  = BOFF_GB + (size_t)NB*4*CK*DD;    // [8][6][64][256]  P (eta-scaled)

__device__ __forceinline__ int bigIdx(int m){ return (m==5)?3:m; }

__device__ __forceinline__ float geluf(float z){
  return 0.5f*z*(1.0f + erff(z*0.70710678118654752440f));
}
__device__ __forceinline__ float dgeluf(float z){
  float cdf = 0.5f*(1.0f + erff(z*0.70710678118654752440f));
  float pdf = expf(-0.5f*z*z)*0.39894228040143267794f;
  return cdf + z*pdf;
}
__device__ __forceinline__ float bfu(unsigned short u){
  unsigned int v = ((unsigned int)u)<<16;
  return __uint_as_float(v);
}
__device__ __forceinline__ float wsum(float v){
  #pragma unroll
  for (int off=32; off>0; off>>=1) v += __shfl_xor(v, off, 64);
  return v;
}

// per-b barrier: 32 blocks, monotone counter (no reset). Release/acquire via
// device-scope fences. BOUNDED spin: residency failure -> diagnosable wrong
// answer instead of a hung container.
__device__ __forceinline__ void bbar(unsigned int* cnt, unsigned int target){
  __syncthreads();
  if (threadIdx.x == 0){
    __threadfence();                              // release our writes
    atomicAdd(cnt, 1u);                           // device-scope arrive
    unsigned int it = 0;
    while (__hip_atomic_load(cnt, __ATOMIC_RELAXED, __HIP_MEMORY_SCOPE_AGENT) < target
           && ++it < (1u<<18))
      __builtin_amdgcn_s_sleep(2);
    __threadfence();                              // acquire others' writes
  }
  __syncthreads();
}

// 16 FMAs for one 4-row group at column offset kk, W quad in registers
__device__ __forceinline__ void fma16(const float* __restrict__ sA, int row0, int kk,
      const float4& q0, const float4& q1, const float4& q2, const float4& q3,
      float acc[4][4]){
  #pragma unroll
  for (int rr=0; rr<4; rr++){
    float4 a = *(const float4*)(sA + (row0+rr)*260 + kk);
    acc[rr][0] += a.x*q0.x + a.y*q0.y + a.z*q0.z + a.w*q0.w;
    acc[rr][1] += a.x*q1.x + a.y*q1.y + a.z*q1.z + a.w*q1.w;
    acc[rr][2] += a.x*q2.x + a.y*q2.y + a.z*q2.z + a.w*q2.w;
    acc[rr][3] += a.x*q3.x + a.y*q3.y + a.z*q3.z + a.w*q3.w;
  }
}

// GEMM, software-pipelined depth 2: W loads for step kk+8 issue before the
// FMAs of step kk -> ~8 outstanding global_load_dwordx4 per wave (MLP fix).
// acc[rr][j] += sum_k A[rg*4+rr][k] * Wm[(cg+64j)*DD + k], A in LDS stride 260
__device__ __forceinline__ void gfull(const float* __restrict__ sA,
      const float* __restrict__ Wm, int cg, int rg, float acc[4][4]){
  const float* p0 = Wm + (size_t)cg*DD;
  const float* p1 = p0 + (size_t)64*DD;
  const float* p2 = p0 + (size_t)128*DD;
  const float* p3 = p0 + (size_t)192*DD;
  const int row0 = rg*4;
  float4 a0 = *(const float4*)(p0);   float4 a1 = *(const float4*)(p1);
  float4 a2 = *(const float4*)(p2);   float4 a3 = *(const float4*)(p3);
  float4 b0 = *(const float4*)(p0+4); float4 b1 = *(const float4*)(p1+4);
  float4 b2 = *(const float4*)(p2+4); float4 b3 = *(const float4*)(p3+4);
  #pragma unroll
  for (int kk=0; kk<248; kk+=8){
    float4 c0 = *(const float4*)(p0+kk+8);  float4 c1 = *(const float4*)(p1+kk+8);
    float4 c2 = *(const float4*)(p2+kk+8);  float4 c3 = *(const float4*)(p3+kk+8);
    float4 d0 = *(const float4*)(p0+kk+12); float4 d1 = *(const float4*)(p1+kk+12);
    float4 d2 = *(const float4*)(p2+kk+12); float4 d3 = *(const float4*)(p3+kk+12);
    fma16(sA, row0, kk,   a0,a1,a2,a3, acc);
    fma16(sA, row0, kk+4, b0,b1,b2,b3, acc);
    a0=c0; a1=c1; a2=c2; a3=c3;
    b0=d0; b1=d1; b2=d2; b3=d3;
  }
  fma16(sA, row0, 248, a0,a1,a2,a3, acc);
  fma16(sA, row0, 252, b0,b1,b2,b3, acc);
}

// GEMM (non-transposed W), software-pipelined depth 1:
// acc[rr][j] += sum_o A[rg*4+rr][o] * Wm[o*DD + cg+64j]
__device__ __forceinline__ void gfullT(const float* __restrict__ sA,
      const float* __restrict__ Wm, int cg, int rg, float acc[4][4]){
  const int row0 = rg*4;
  float wv[4][4], nv[4][4];
  #pragma unroll
  for (int s=0;s<4;s++)
    #pragma unroll
    for (int j=0;j<4;j++) wv[s][j] = Wm[(size_t)s*DD + cg+64*j];
  #pragma unroll
  for (int kk=0; kk<252; kk+=4){
    #pragma unroll
    for (int s=0;s<4;s++)
      #pragma unroll
      for (int j=0;j<4;j++) nv[s][j] = Wm[(size_t)(kk+4+s)*DD + cg+64*j];
    #pragma unroll
    for (int rr=0;rr<4;rr++){
      float4 a = *(const float4*)(sA + (row0+rr)*260 + kk);
      #pragma unroll
      for (int j=0;j<4;j++)
        acc[rr][j] += a.x*wv[0][j] + a.y*wv[1][j] + a.z*wv[2][j] + a.w*wv[3][j];
    }
    #pragma unroll
    for (int s=0;s<4;s++)
      #pragma unroll
      for (int j=0;j<4;j++) wv[s][j] = nv[s][j];
  }
  #pragma unroll
  for (int rr=0;rr<4;rr++){
    float4 a = *(const float4*)(sA + (row0+rr)*260 + 252);
    #pragma unroll
    for (int j=0;j<4;j++)
      acc[rr][j] += a.x*wv[0][j] + a.y*wv[1][j] + a.z*wv[2][j] + a.w*wv[3][j];
  }
}

// ---------------- init ----------------
__global__ __launch_bounds__(256) void initk(float* __restrict__ W,
  const float* kw1, const float* kw2, const float* vw1, const float* vw2,
  const float* qw1, const float* qw2, const float* ew1, const float* ew2,
  const float* ewsk, const float* aw1, const float* aw2, const float* awsk,
  const float* mw1, const float* mw2)
{
  int b = blockIdx.x/6, m = blockIdx.x%6;
  const float *w1s=nullptr,*w2s=nullptr,*wsks=nullptr;
  switch(m){
    case 0: w1s=kw1; w2s=kw2; break;
    case 1: w1s=vw1; w2s=vw2; break;
    case 2: w1s=qw1; w2s=qw2; break;
    case 3: w1s=ew1; w2s=ew2; wsks=ewsk; break;
    case 4: w1s=aw1; w2s=aw2; wsks=awsk; break;
    default: w1s=mw1; w2s=mw2; break;
  }
  if (m==0 && threadIdx.x==0)
    ((unsigned int*)(W + OFF_BARC))[b] = 0u;     // reset per-b barrier counter
  float* w2d = W + OFF_W2 + ((size_t)b*6+m)*MSZ;
  for (size_t i=threadIdx.x; i<MSZ; i+=256) w2d[i] = w2s[i];
  if (m==3 || m==4){
    int sm = m-3;
    float* w1d = W + OFF_W1S + ((size_t)b*2+sm)*DD;
    float* wsd = W + OFF_WSK + ((size_t)b*2+sm)*DD;
    for (int i=threadIdx.x;i<DD;i+=256){ w1d[i]=w1s[i]; wsd[i]=wsks[i]; }
  } else {
    float* w1d = W + OFF_W1B + ((size_t)b*4+bigIdx(m))*MSZ;
    for (size_t i=threadIdx.x;i<MSZ;i+=256) w1d[i] = w1s[i];
  }
}

// ---------------- persistent kernel: 8 per-b pipelines, XCD-local ----------------
// grid = 256 blocks; b = blk&7 -> with round-robin wg->XCD dispatch, the 32
// blocks of batch b land on XCD b (weights L2-resident; perf heuristic only;
// correctness rests on the device-scope fences in bbar).
// (256,1): no VGPR cap; 1 block/CU, 4 waves, ~12.4% occupancy by design.
__global__ __launch_bounds__(256, 1) void pers(const float* __restrict__ x,
        float* __restrict__ W, __hip_bfloat16* __restrict__ B,
        float* __restrict__ out)
{
  const int blk = blockIdx.x, tid = threadIdx.x;
  const int b = blk & 7, wb = blk >> 3;
  const int cg = tid & 63, rg = tid >> 6;
  unsigned int* cnt = ((unsigned int*)(W + OFF_BARC)) + b;
  unsigned int bar = 0;
  __shared__ __align__(16) float sMem[2*16*260];   // sX | sY (phase3 reuses as sT)
  __shared__ float sSc[64];
  __shared__ float sEt[64], sSk[64];
  float* sX = sMem;
  float* sY = sMem + 16*260;

  for (int ck=0; ck<NCK; ck++){
    // ================= phase 1: forward heads + row stats (20 tasks/b) =========
    for (int task=wb; task<20; task+=32){
      int m = task>>2, t0 = (task&3)*16;
      const float* xp = x + ((size_t)b*TT + (size_t)ck*CK + t0)*DD;
      for (int l=tid; l<1024; l+=256){
        int tl = l>>6, ii = (l&63)<<2;
        *(float4*)(sX + tl*260 + ii) = *(const float4*)(xp + (size_t)tl*DD + ii);
      }
      __syncthreads();
      const float* w2 = W + OFF_W2 + ((size_t)b*6+m)*MSZ;
      float acc1[4][4];
      #pragma unroll
      for (int i=0;i<4;i++){ acc1[i][0]=acc1[i][1]=acc1[i][2]=acc1[i][3]=0.0f; }
      gfull(sX, w2, cg, rg, acc1);
      if (m < 3){
        #pragma unroll
        for (int rr=0;rr<4;rr++)
          #pragma unroll
          for (int j=0;j<4;j++)
            sY[(rg*4+rr)*260 + cg+64*j] = geluf(acc1[rr][j]);
        __syncthreads();
        const float* w1 = W + OFF_W1B + ((size_t)b*4+m)*MSZ;
        float acc2[4][4];
        #pragma unroll
        for (int i=0;i<4;i++){ acc2[i][0]=acc2[i][1]=acc2[i][2]=acc2[i][3]=0.0f; }
        gfull(sY, w1, cg, rg, acc2);
        __hip_bfloat16* fd = B + BOFF_F + ((size_t)m*NB + b)*CK*DD;
        float p[4];
        #pragma unroll
        for (int rr=0;rr<4;rr++){
          float ps = 0.0f;
          #pragma unroll
          for (int j=0;j<4;j++){
            int col = cg+64*j;
            float F = sX[(rg*4+rr)*260 + col] + acc2[rr][j];
            fd[(size_t)(t0+rg*4+rr)*DD + col] = __float2bfloat16(F);
            ps += (m==1) ? F : F*F;
          }
          p[rr] = ps;
        }
        #pragma unroll
        for (int rr=0;rr<4;rr++){
          float v = wsum(p[rr]);
          if (cg == 0){
            int t = t0 + rg*4 + rr;
            if (m==0)      W[OFF_SCK + (size_t)b*CK + t] = 1.0f/fmaxf(sqrtf(v), EPSV);
            else if (m==2) W[OFF_SCQ + (size_t)b*CK + t] = 1.0f/fmaxf(sqrtf(v), EPSV);
            else           W[OFF_VSUM+ (size_t)b*CK + t] = v;
          }
        }
      } else {
        int sm = m-3;
        const float* w1s = W + OFF_W1S + ((size_t)b*2+sm)*DD;
        const float* wsk = W + OFF_WSK + ((size_t)b*2+sm)*DD;
        float p[4];
        #pragma unroll
        for (int rr=0;rr<4;rr++){
          float ps = 0.0f;
          #pragma unroll
          for (int j=0;j<4;j++){
            int col = cg+64*j;
            ps += sX[(rg*4+rr)*260+col]*wsk[col] + geluf(acc1[rr][j])*w1s[col];
          }
          p[rr] = ps;
        }
        #pragma unroll
        for (int rr=0;rr<4;rr++){
          float v = wsum(p[rr]);
          if (cg == 0){
            int t = t0 + rg*4 + rr;
            if (sm==0){
              float sp = (v>0.0f) ? (v + log1pf(expf(-v))) : log1pf(expf(v));
              W[OFF_ETA + (size_t)b*CK + t] = sp*ETA_SC;
            } else {
              W[OFF_SALP + (size_t)b*CK + t] = 1.0f/(1.0f+expf(-v));
            }
          }
        }
      }
      __syncthreads();
    }
    bar += 32; bbar(cnt, bar);

    // ================= phase 2: update-forward chains + output (29 tasks/b) ====
    for (int task=wb; task<29; task+=32){
      if (task < 28){
        int chn = task>>2, t0 = (task&3)*16;
        bool isq = (chn==6);
        const unsigned short* fsrc = (const unsigned short*)
            (B + BOFF_F + ((size_t)(isq?2:0)*NB + b)*CK*DD + (size_t)t0*DD);
        const float* scp = W + (isq?OFF_SCQ:OFF_SCK) + (size_t)b*CK + t0;
        if (tid < 16)       sSc[tid] = scp[tid];
        else if (tid < 32)  sSc[tid] = W[OFF_ETA + (size_t)b*CK + t0 + (tid-16)];
        else if (tid < 48)  sSc[tid] = W[OFF_VSUM+ (size_t)b*CK + t0 + (tid-32)];
        __syncthreads();
        for (int l=tid; l<1024; l+=256){
          int tl = l>>6, ii = (l&63)<<2;
          ushort4 u = *(const ushort4*)(fsrc + (size_t)tl*DD + ii);
          float s = sSc[tl];
          float4 t4;
          t4.x = bfu(u.x)*s; t4.y = bfu(u.y)*s; t4.z = bfu(u.z)*s; t4.w = bfu(u.w)*s;
          *(float4*)(sX + tl*260 + ii) = t4;
        }
        __syncthreads();
        int m2 = isq ? 5 : chn;
        const float* w2 = W + OFF_W2 + ((size_t)b*6+m2)*MSZ;
        float acc1[4][4];
        #pragma unroll
        for (int i=0;i<4;i++){ acc1[i][0]=acc1[i][1]=acc1[i][2]=acc1[i][3]=0.0f; }
        gfull(sX, w2, cg, rg, acc1);   // zu (or zo)

        if (chn==0 || chn==1 || chn==2 || chn==5){
          int mi = (chn==5)?3:chn;
          __hip_bfloat16* hd = B + BOFF_H + ((size_t)(b*6+chn))*CK*DD;
          #pragma unroll
          for (int rr=0;rr<4;rr++)
            #pragma unroll
            for (int j=0;j<4;j++){
              float h = geluf(acc1[rr][j]);
              sY[(rg*4+rr)*260 + cg+64*j] = h;
              hd[(size_t)(t0+rg*4+rr)*DD + cg+64*j] = __float2bfloat16(h);
            }
          __syncthreads();
          const float* w1 = W + OFF_W1B + ((size_t)b*4+mi)*MSZ;
          float acc2[4][4];
          #pragma unroll
          for (int i=0;i<4;i++){ acc2[i][0]=acc2[i][1]=acc2[i][2]=acc2[i][3]=0.0f; }
          gfull(sY, w1, cg, rg, acc2);
          __syncthreads();   // all waves done reading sY(h) before overwrite with g
          const unsigned short* fv = (const unsigned short*)
              (B + BOFF_F + ((size_t)1*NB + b)*CK*DD + (size_t)t0*DD);
          __hip_bfloat16* gd = B + BOFF_GB + ((size_t)(b*4+mi))*CK*DD;
          #pragma unroll
          for (int rr=0;rr<4;rr++)
            #pragma unroll
            for (int j=0;j<4;j++){
              int col = cg+64*j;
              float g = 2.0f*( sX[(rg*4+rr)*260+col] + acc2[rr][j]
                               - bfu(fv[(size_t)(rg*4+rr)*DD+col]) );
              sY[(rg*4+rr)*260+col] = g;
              gd[(size_t)(t0+rg*4+rr)*DD + col] = __float2bfloat16(g);
            }
          __syncthreads();
          float accp[4][4];
          #pragma unroll
          for (int i=0;i<4;i++){ accp[i][0]=accp[i][1]=accp[i][2]=accp[i][3]=0.0f; }
          gfullT(sY, w1, cg, rg, accp);   // pre = g @ w1
          __hip_bfloat16* pd2 = B + BOFF_P + ((size_t)(b*6+chn))*CK*DD;
          #pragma unroll
          for (int rr=0;rr<4;rr++){
            float et = sSc[16 + rg*4+rr];
            #pragma unroll
            for (int j=0;j<4;j++)
              pd2[(size_t)(t0+rg*4+rr)*DD + cg+64*j] =
                __float2bfloat16(accp[rr][j]*dgeluf(acc1[rr][j])*et);
          }
        } else if (chn==6){
          #pragma unroll
          for (int rr=0;rr<4;rr++)
            #pragma unroll
            for (int j=0;j<4;j++)
              sY[(rg*4+rr)*260 + cg+64*j] = geluf(acc1[rr][j]);
          __syncthreads();
          const float* w1 = W + OFF_W1B + ((size_t)b*4+3)*MSZ;
          float acc2[4][4];
          #pragma unroll
          for (int i=0;i<4;i++){ acc2[i][0]=acc2[i][1]=acc2[i][2]=acc2[i][3]=0.0f; }
          gfull(sY, w1, cg, rg, acc2);
          float* op = out + ((size_t)b*TT + (size_t)ck*CK + t0)*DD;
          #pragma unroll
          for (int rr=0;rr<4;rr++)
            #pragma unroll
            for (int j=0;j<4;j++){
              int col = cg+64*j;
              op[(size_t)(rg*4+rr)*DD + col] = sX[(rg*4+rr)*260+col] + acc2[rr][j];
            }
        } else {
          int sm = chn-3;
          __hip_bfloat16* hd = B + BOFF_H + ((size_t)(b*6+chn))*CK*DD;
          const float* w1s = W + OFF_W1S + ((size_t)b*2+sm)*DD;
          const float* wsk = W + OFF_WSK + ((size_t)b*2+sm)*DD;
          float p[4];
          #pragma unroll
          for (int rr=0;rr<4;rr++){
            float ps = 0.0f;
            #pragma unroll
            for (int j=0;j<4;j++){
              int col = cg+64*j;
              float h = geluf(acc1[rr][j]);
              hd[(size_t)(t0+rg*4+rr)*DD + col] = __float2bfloat16(h);
              ps += sX[(rg*4+rr)*260+col]*wsk[col] + h*w1s[col];
            }
            p[rr] = ps;
          }
          __hip_bfloat16* pd2 = B + BOFF_P + ((size_t)(b*6+chn))*CK*DD;
          #pragma unroll
          for (int rr=0;rr<4;rr++){
            float f = wsum(p[rr]);                      // all lanes hold row value
            int t = t0 + rg*4 + rr;
            float gs = 2.0f*(256.0f*f - sSc[32 + rg*4+rr]);
            if (cg == 0) W[OFF_GS + ((size_t)b*2+sm)*CK + t] = gs;
            float ge = gs * sSc[16 + rg*4+rr];          // g*eta
            #pragma unroll
            for (int j=0;j<4;j++){
              int col = cg+64*j;
              pd2[(size_t)t*DD + col] =
                __float2bfloat16(ge*w1s[col]*dgeluf(acc1[rr][j]));
            }
          }
        }
      } else {
        // abar = prod_t sigmoid(alpha_t)
        if (tid < 64){
          float v = W[OFF_SALP + (size_t)b*CK + tid];
          #pragma unroll
          for (int off=32; off>0; off>>=1) v *= __shfl_xor(v, off, 64);
          if (tid == 0) W[OFF_ABAR + b] = v;
        }
      }
      __syncthreads();
    }
    bar += 32; bbar(cnt, bar);

    // ================= phase 3: state updates (82 half-tasks/b) ================
    {
      if (tid < 64){
        sEt[tid] = W[OFF_ETA + (size_t)b*CK + tid];
        sSk[tid] = W[OFF_SCK + (size_t)b*CK + tid];
      }
      __syncthreads();
      float ab = W[OFF_ABAR + b];
      const unsigned short* fk = (const unsigned short*)(B + BOFF_F + ((size_t)0*NB+b)*CK*DD);
      float* sT = sMem;      // 32*68 floats used
      int c = tid;
      for (int task=wb; task<82; task+=32){
        if (task < 32){
          // w1[o0..o0+31][c] -= sum_t g[t,o]*eta[t]*h[t,c]
          int mi = task>>3, o0 = (task&7)*32;
          int m = (mi==3)?5:mi;
          const unsigned short* hb = (const unsigned short*)(B + BOFF_H + ((size_t)(b*6+m))*CK*DD);
          const unsigned short* gb = (const unsigned short*)(B + BOFF_GB + ((size_t)(b*4+mi))*CK*DD);
          float* w1 = W + OFF_W1B + ((size_t)b*4+mi)*MSZ;
          float hv[64];
          #pragma unroll
          for (int t=0;t<64;t++) hv[t] = bfu(hb[(size_t)t*DD + c]);
          for (int l=tid; l<2048; l+=256){
            int t=l>>5, oo=l&31;
            sT[oo*68+t] = bfu(gb[(size_t)t*DD + o0+oo]) * sEt[t];
          }
          __syncthreads();
          for (int oo=0; oo<32; oo++){
            float s = 0.0f;
            #pragma unroll
            for (int t4=0; t4<16; t4++){
              float4 g4 = *(const float4*)(sT + oo*68 + t4*4);
              s += g4.x*hv[4*t4] + g4.y*hv[4*t4+1] + g4.z*hv[4*t4+2] + g4.w*hv[4*t4+3];
            }
            size_t idx = (size_t)(o0+oo)*DD + c;
            w1[idx] = ab*w1[idx] - s;
          }
        } else if (task < 80){
          // w2[h0..h0+31][c] -= sum_t P[t,h]*k[t,c]
          int r = task-32, m = r>>3, h0 = (r&7)*32;
          const unsigned short* pd2 = (const unsigned short*)(B + BOFF_P + ((size_t)(b*6+m))*CK*DD);
          float* w2 = W + OFF_W2 + ((size_t)b*6+m)*MSZ;
          float kc[64];
          #pragma unroll
          for (int t=0;t<64;t++) kc[t] = bfu(fk[(size_t)t*DD+c]) * sSk[t];
          for (int l=tid; l<2048; l+=256){
            int t=l>>5, hh=l&31;
            sT[hh*68+t] = bfu(pd2[(size_t)t*DD + h0+hh]);
          }
          __syncthreads();
          for (int hh=0; hh<32; hh++){
            float s = 0.0f;
            #pragma unroll
            for (int t4=0; t4<16; t4++){
              float4 p4 = *(const float4*)(sT + hh*68 + t4*4);
              s += p4.x*kc[4*t4] + p4.y*kc[4*t4+1] + p4.z*kc[4*t4+2] + p4.w*kc[4*t4+3];
            }
            size_t idx = (size_t)(h0+hh)*DD + c;
            w2[idx] = ab*w2[idx] - s;
          }
        } else {
          // small-state updates
          int sm = task-80, m = 3+sm;
          const unsigned short* hb = (const unsigned short*)(B + BOFF_H + ((size_t)(b*6+m))*CK*DD);
          float s1=0.0f, s2=0.0f;
          #pragma unroll
          for (int t=0;t<64;t++){
            float ge = W[OFF_GS + ((size_t)b*2+sm)*CK + t] * sEt[t];
            s1 += ge * bfu(hb[(size_t)t*DD+c]);
            s2 += ge * bfu(fk[(size_t)t*DD+c]) * sSk[t];
          }
          float* w1s = W + OFF_W1S + ((size_t)b*2+sm)*DD;
          float* wskp= W + OFF_WSK + ((size_t)b*2+sm)*DD;
          w1s[c]  = ab*w1s[c]  - s1;
          wskp[c] = ab*wskp[c] - s2;
        }
        __syncthreads();
      }
    }
    bar += 32; bbar(cnt, bar);
  }
}

// ---------------- host ----------------
extern "C" void kernel_launch(void* const* d_in, const int* in_sizes, int n_in,
                              void* d_out, int out_size, void* d_ws, size_t ws_size,
                              hipStream_t stream){
  const float* x = (const float*)d_in[0];
  float* W = (float*)d_ws;
  __hip_bfloat16* B = (__hip_bfloat16*)(W + FTOT);
  float* out = (float*)d_out;

  initk<<<NB*6, 256, 0, stream>>>(W,
      (const float*)d_in[1], (const float*)d_in[2],
      (const float*)d_in[3], (const float*)d_in[4],
      (const float*)d_in[5], (const float*)d_in[6],
      (const float*)d_in[7], (const float*)d_in[8],
      (const float*)d_in[9], (const float*)d_in[10],
      (const float*)d_in[11], (const float*)d_in[12],
      (const float*)d_in[13], (const float*)d_in[14]);

  pers<<<256, 256, 0, stream>>>(x, W, B, out);
}

// Round 7
// 15063.292 us; speedup vs baseline: 5.4521x; 5.4521x over previous
//
#include <hip/hip_runtime.h>
#include <hip/hip_bf16.h>
#include <math.h>

// ---------------- problem constants ----------------
constexpr int NB  = 8;
constexpr int TT  = 4096;
constexpr int DD  = 256;
constexpr int CK  = 64;
constexpr int NCK = 64;
constexpr float ETA_SC = 1e-3f;
constexpr float EPSV   = 1e-6f;

constexpr size_t MSZ = (size_t)DD*DD;   // 65536

// ---------- fp32 region (element offsets into float* W) ----------
constexpr size_t OFF_W2  = 0;                               // [8][6][256*256]
constexpr size_t OFF_W1B = OFF_W2  + (size_t)NB*6*MSZ;      // [8][4][256*256]  (k,v,q,mem)
constexpr size_t OFF_W1S = OFF_W1B + (size_t)NB*4*MSZ;      // [8][2][256]
constexpr size_t OFF_WSK = OFF_W1S + (size_t)NB*2*DD;       // [8][2][256]
constexpr size_t OFF_SCK = OFF_WSK + (size_t)NB*2*DD;       // [8][64]
constexpr size_t OFF_SCQ = OFF_SCK + (size_t)NB*CK;         // [8][64]
constexpr size_t OFF_VSUM= OFF_SCQ + (size_t)NB*CK;         // [8][64]
constexpr size_t OFF_ETA = OFF_VSUM+ (size_t)NB*CK;         // [8][64]
constexpr size_t OFF_GS  = OFF_ETA + (size_t)NB*CK;         // [8][2][64]
constexpr size_t OFF_SALP= OFF_GS  + (size_t)NB*2*CK;       // [8][64] sigmoid(alpha)
constexpr size_t OFF_ABAR= OFF_SALP+ (size_t)NB*CK;         // [8]
constexpr size_t OFF_BARC= OFF_ABAR + NB;                   // [8] per-b barrier counters (uint)
constexpr size_t FTOT    = OFF_BARC + NB;

// ---------- bf16 region (element offsets into __hip_bfloat16* B) ----------
constexpr size_t BOFF_F  = 0;                               // [3][8][64][256]  F_k,F_v,F_q
constexpr size_t BOFF_H  = BOFF_F  + (size_t)3*NB*CK*DD;    // [8][6][64][256]  h=gelu(zu)
constexpr size_t BOFF_GB = BOFF_H  + (size_t)NB*6*CK*DD;    // [8][4][64][256]  g (big mems)
constexpr size_t BOFF_P  = BOFF_GB + (size_t)NB*4*CK*DD;    // [8][6][64][256]  P (eta-scaled)

__device__ __forceinline__ int bigIdx(int m){ return (m==5)?3:m; }

__device__ __forceinline__ float geluf(float z){
  return 0.5f*z*(1.0f + erff(z*0.70710678118654752440f));
}
__device__ __forceinline__ float dgeluf(float z){
  float cdf = 0.5f*(1.0f + erff(z*0.70710678118654752440f));
  float pdf = expf(-0.5f*z*z)*0.39894228040143267794f;
  return cdf + z*pdf;
}
__device__ __forceinline__ float bfu(unsigned short u){
  unsigned int v = ((unsigned int)u)<<16;
  return __uint_as_float(v);
}
__device__ __forceinline__ float wsum(float v){
  #pragma unroll
  for (int off=32; off>0; off>>=1) v += __shfl_xor(v, off, 64);
  return v;
}

// per-b barrier: 32 blocks, monotone counter (no reset). Release/acquire via
// device-scope fences (correctness does NOT depend on XCD placement).
// BOUNDED spin: residency failure -> diagnosable wrong answer, not a hang.
__device__ __forceinline__ void bbar(unsigned int* cnt, unsigned int target){
  __syncthreads();
  if (threadIdx.x == 0){
    __threadfence();                              // release our writes
    atomicAdd(cnt, 1u);                           // device-scope arrive
    unsigned int it = 0;
    while (__hip_atomic_load(cnt, __ATOMIC_RELAXED, __HIP_MEMORY_SCOPE_AGENT) < target
           && ++it < (1u<<18))
      __builtin_amdgcn_s_sleep(2);
    __threadfence();                              // acquire others' writes
  }
  __syncthreads();
}

// GEMM: acc[rr][j] += sum_k A[rg*4+rr][k] * Wm[(cg+64j)*DD + k], A in LDS stride 260
// (r4's simple form -- NO manual pipelining: kernel sits at the 256-VGPR cliff,
//  r6 proved deeper rotation spills to scratch: WRITE 1.67->15.3 GB, 82ms.)
__device__ __forceinline__ void gfull(const float* __restrict__ sA,
      const float* __restrict__ Wm, int cg, int rg, float acc[4][4]){
  #pragma unroll 4
  for (int kk=0; kk<256; kk+=4){
    float4 w0 = *(const float4*)(Wm + (size_t)(cg      )*DD + kk);
    float4 w1 = *(const float4*)(Wm + (size_t)(cg +  64)*DD + kk);
    float4 w2 = *(const float4*)(Wm + (size_t)(cg + 128)*DD + kk);
    float4 w3 = *(const float4*)(Wm + (size_t)(cg + 192)*DD + kk);
    #pragma unroll
    for (int rr=0; rr<4; rr++){
      float4 a = *(const float4*)(sA + (rg*4+rr)*260 + kk);
      acc[rr][0] += a.x*w0.x + a.y*w0.y + a.z*w0.z + a.w*w0.w;
      acc[rr][1] += a.x*w1.x + a.y*w1.y + a.z*w1.z + a.w*w1.w;
      acc[rr][2] += a.x*w2.x + a.y*w2.y + a.z*w2.z + a.w*w2.w;
      acc[rr][3] += a.x*w3.x + a.y*w3.y + a.z*w3.z + a.w*w3.w;
    }
  }
}

// GEMM (non-transposed W): acc[rr][j] += sum_o A[rg*4+rr][o] * Wm[o*DD + cg+64j]
__device__ __forceinline__ void gfullT(const float* __restrict__ sA,
      const float* __restrict__ Wm, int cg, int rg, float acc[4][4]){
  #pragma unroll 2
  for (int kk=0; kk<256; kk+=4){
    float wv[4][4];
    #pragma unroll
    for (int s=0;s<4;s++)
      #pragma unroll
      for (int j=0;j<4;j++)
        wv[s][j] = Wm[(size_t)(kk+s)*DD + cg+64*j];
    #pragma unroll
    for (int rr=0;rr<4;rr++){
      float4 a = *(const float4*)(sA + (rg*4+rr)*260 + kk);
      #pragma unroll
      for (int j=0;j<4;j++)
        acc[rr][j] += a.x*wv[0][j] + a.y*wv[1][j] + a.z*wv[2][j] + a.w*wv[3][j];
    }
  }
}

// ---------------- init ----------------
__global__ __launch_bounds__(256) void initk(float* __restrict__ W,
  const float* kw1, const float* kw2, const float* vw1, const float* vw2,
  const float* qw1, const float* qw2, const float* ew1, const float* ew2,
  const float* ewsk, const float* aw1, const float* aw2, const float* awsk,
  const float* mw1, const float* mw2)
{
  int b = blockIdx.x/6, m = blockIdx.x%6;
  const float *w1s=nullptr,*w2s=nullptr,*wsks=nullptr;
  switch(m){
    case 0: w1s=kw1; w2s=kw2; break;
    case 1: w1s=vw1; w2s=vw2; break;
    case 2: w1s=qw1; w2s=qw2; break;
    case 3: w1s=ew1; w2s=ew2; wsks=ewsk; break;
    case 4: w1s=aw1; w2s=aw2; wsks=awsk; break;
    default: w1s=mw1; w2s=mw2; break;
  }
  if (m==0 && threadIdx.x==0)
    ((unsigned int*)(W + OFF_BARC))[b] = 0u;     // reset per-b barrier counter
  float* w2d = W + OFF_W2 + ((size_t)b*6+m)*MSZ;
  for (size_t i=threadIdx.x; i<MSZ; i+=256) w2d[i] = w2s[i];
  if (m==3 || m==4){
    int sm = m-3;
    float* w1d = W + OFF_W1S + ((size_t)b*2+sm)*DD;
    float* wsd = W + OFF_WSK + ((size_t)b*2+sm)*DD;
    for (int i=threadIdx.x;i<DD;i+=256){ w1d[i]=w1s[i]; wsd[i]=wsks[i]; }
  } else {
    float* w1d = W + OFF_W1B + ((size_t)b*4+bigIdx(m))*MSZ;
    for (size_t i=threadIdx.x;i<MSZ;i+=256) w1d[i] = w1s[i];
  }
}

// ---------------- persistent kernel: 8 per-b pipelines, XCD-local ----------------
// grid = 256 blocks; b = blk&7 -> with round-robin wg->XCD dispatch, the 32
// blocks of batch b land on XCD b (per-b weights ~2.6MB < 4MB XCD-L2: resident).
// Proven r5: FETCH 6.7 -> 2.4 GB. Perf heuristic only; correctness rests on
// the device-scope fences in bbar (G16).
// (256,1): no VGPR cap; r4's exact R=4 task shapes (17.6ms structure).
__global__ __launch_bounds__(256, 1) void pers(const float* __restrict__ x,
        float* __restrict__ W, __hip_bfloat16* __restrict__ B,
        float* __restrict__ out)
{
  const int blk = blockIdx.x, tid = threadIdx.x;
  const int b = blk & 7, wb = blk >> 3;
  const int cg = tid & 63, rg = tid >> 6;
  unsigned int* cnt = ((unsigned int*)(W + OFF_BARC)) + b;
  unsigned int bar = 0;
  __shared__ __align__(16) float sMem[2*16*260];   // sX | sY (phase3 reuses as sT)
  __shared__ float sSc[64];
  __shared__ float sEt[64], sSk[64];
  float* sX = sMem;
  float* sY = sMem + 16*260;

  for (int ck=0; ck<NCK; ck++){
    // ================= phase 1: forward heads + row stats (20 tasks/b) =========
    for (int task=wb; task<20; task+=32){
      int m = task>>2, t0 = (task&3)*16;
      const float* xp = x + ((size_t)b*TT + (size_t)ck*CK + t0)*DD;
      for (int l=tid; l<1024; l+=256){
        int tl = l>>6, ii = (l&63)<<2;
        *(float4*)(sX + tl*260 + ii) = *(const float4*)(xp + (size_t)tl*DD + ii);
      }
      __syncthreads();
      const float* w2 = W + OFF_W2 + ((size_t)b*6+m)*MSZ;
      float acc1[4][4];
      #pragma unroll
      for (int i=0;i<4;i++){ acc1[i][0]=acc1[i][1]=acc1[i][2]=acc1[i][3]=0.0f; }
      gfull(sX, w2, cg, rg, acc1);
      if (m < 3){
        #pragma unroll
        for (int rr=0;rr<4;rr++)
          #pragma unroll
          for (int j=0;j<4;j++)
            sY[(rg*4+rr)*260 + cg+64*j] = geluf(acc1[rr][j]);
        __syncthreads();
        const float* w1 = W + OFF_W1B + ((size_t)b*4+m)*MSZ;
        float acc2[4][4];
        #pragma unroll
        for (int i=0;i<4;i++){ acc2[i][0]=acc2[i][1]=acc2[i][2]=acc2[i][3]=0.0f; }
        gfull(sY, w1, cg, rg, acc2);
        __hip_bfloat16* fd = B + BOFF_F + ((size_t)m*NB + b)*CK*DD;
        float p[4];
        #pragma unroll
        for (int rr=0;rr<4;rr++){
          float ps = 0.0f;
          #pragma unroll
          for (int j=0;j<4;j++){
            int col = cg+64*j;
            float F = sX[(rg*4+rr)*260 + col] + acc2[rr][j];
            fd[(size_t)(t0+rg*4+rr)*DD + col] = __float2bfloat16(F);
            ps += (m==1) ? F : F*F;
          }
          p[rr] = ps;
        }
        #pragma unroll
        for (int rr=0;rr<4;rr++){
          float v = wsum(p[rr]);
          if (cg == 0){
            int t = t0 + rg*4 + rr;
            if (m==0)      W[OFF_SCK + (size_t)b*CK + t] = 1.0f/fmaxf(sqrtf(v), EPSV);
            else if (m==2) W[OFF_SCQ + (size_t)b*CK + t] = 1.0f/fmaxf(sqrtf(v), EPSV);
            else           W[OFF_VSUM+ (size_t)b*CK + t] = v;
          }
        }
      } else {
        int sm = m-3;
        const float* w1s = W + OFF_W1S + ((size_t)b*2+sm)*DD;
        const float* wsk = W + OFF_WSK + ((size_t)b*2+sm)*DD;
        float p[4];
        #pragma unroll
        for (int rr=0;rr<4;rr++){
          float ps = 0.0f;
          #pragma unroll
          for (int j=0;j<4;j++){
            int col = cg+64*j;
            ps += sX[(rg*4+rr)*260+col]*wsk[col] + geluf(acc1[rr][j])*w1s[col];
          }
          p[rr] = ps;
        }
        #pragma unroll
        for (int rr=0;rr<4;rr++){
          float v = wsum(p[rr]);
          if (cg == 0){
            int t = t0 + rg*4 + rr;
            if (sm==0){
              float sp = (v>0.0f) ? (v + log1pf(expf(-v))) : log1pf(expf(v));
              W[OFF_ETA + (size_t)b*CK + t] = sp*ETA_SC;
            } else {
              W[OFF_SALP + (size_t)b*CK + t] = 1.0f/(1.0f+expf(-v));
            }
          }
        }
      }
      __syncthreads();
    }
    bar += 32; bbar(cnt, bar);

    // ================= phase 2: update-forward chains + output (29 tasks/b) ====
    for (int task=wb; task<29; task+=32){
      if (task < 28){
        int chn = task>>2, t0 = (task&3)*16;
        bool isq = (chn==6);
        const unsigned short* fsrc = (const unsigned short*)
            (B + BOFF_F + ((size_t)(isq?2:0)*NB + b)*CK*DD + (size_t)t0*DD);
        const float* scp = W + (isq?OFF_SCQ:OFF_SCK) + (size_t)b*CK + t0;
        if (tid < 16)       sSc[tid] = scp[tid];
        else if (tid < 32)  sSc[tid] = W[OFF_ETA + (size_t)b*CK + t0 + (tid-16)];
        else if (tid < 48)  sSc[tid] = W[OFF_VSUM+ (size_t)b*CK + t0 + (tid-32)];
        __syncthreads();
        for (int l=tid; l<1024; l+=256){
          int tl = l>>6, ii = (l&63)<<2;
          ushort4 u = *(const ushort4*)(fsrc + (size_t)tl*DD + ii);
          float s = sSc[tl];
          float4 t4;
          t4.x = bfu(u.x)*s; t4.y = bfu(u.y)*s; t4.z = bfu(u.z)*s; t4.w = bfu(u.w)*s;
          *(float4*)(sX + tl*260 + ii) = t4;
        }
        __syncthreads();
        int m2 = isq ? 5 : chn;
        const float* w2 = W + OFF_W2 + ((size_t)b*6+m2)*MSZ;
        float acc1[4][4];
        #pragma unroll
        for (int i=0;i<4;i++){ acc1[i][0]=acc1[i][1]=acc1[i][2]=acc1[i][3]=0.0f; }
        gfull(sX, w2, cg, rg, acc1);   // zu (or zo)

        if (chn==0 || chn==1 || chn==2 || chn==5){
          int mi = (chn==5)?3:chn;
          __hip_bfloat16* hd = B + BOFF_H + ((size_t)(b*6+chn))*CK*DD;
          #pragma unroll
          for (int rr=0;rr<4;rr++)
            #pragma unroll
            for (int j=0;j<4;j++){
              float h = geluf(acc1[rr][j]);
              sY[(rg*4+rr)*260 + cg+64*j] = h;
              hd[(size_t)(t0+rg*4+rr)*DD + cg+64*j] = __float2bfloat16(h);
            }
          __syncthreads();
          const float* w1 = W + OFF_W1B + ((size_t)b*4+mi)*MSZ;
          float acc2[4][4];
          #pragma unroll
          for (int i=0;i<4;i++){ acc2[i][0]=acc2[i][1]=acc2[i][2]=acc2[i][3]=0.0f; }
          gfull(sY, w1, cg, rg, acc2);
          __syncthreads();   // all waves done reading sY(h) before overwrite with g
          const unsigned short* fv = (const unsigned short*)
              (B + BOFF_F + ((size_t)1*NB + b)*CK*DD + (size_t)t0*DD);
          __hip_bfloat16* gd = B + BOFF_GB + ((size_t)(b*4+mi))*CK*DD;
          #pragma unroll
          for (int rr=0;rr<4;rr++)
            #pragma unroll
            for (int j=0;j<4;j++){
              int col = cg+64*j;
              float g = 2.0f*( sX[(rg*4+rr)*260+col] + acc2[rr][j]
                               - bfu(fv[(size_t)(rg*4+rr)*DD+col]) );
              sY[(rg*4+rr)*260+col] = g;
              gd[(size_t)(t0+rg*4+rr)*DD + col] = __float2bfloat16(g);
            }
          __syncthreads();
          float accp[4][4];
          #pragma unroll
          for (int i=0;i<4;i++){ accp[i][0]=accp[i][1]=accp[i][2]=accp[i][3]=0.0f; }
          gfullT(sY, w1, cg, rg, accp);   // pre = g @ w1
          __hip_bfloat16* pd2 = B + BOFF_P + ((size_t)(b*6+chn))*CK*DD;
          #pragma unroll
          for (int rr=0;rr<4;rr++){
            float et = sSc[16 + rg*4+rr];
            #pragma unroll
            for (int j=0;j<4;j++)
              pd2[(size_t)(t0+rg*4+rr)*DD + cg+64*j] =
                __float2bfloat16(accp[rr][j]*dgeluf(acc1[rr][j])*et);
          }
        } else if (chn==6){
          #pragma unroll
          for (int rr=0;rr<4;rr++)
            #pragma unroll
            for (int j=0;j<4;j++)
              sY[(rg*4+rr)*260 + cg+64*j] = geluf(acc1[rr][j]);
          __syncthreads();
          const float* w1 = W + OFF_W1B + ((size_t)b*4+3)*MSZ;
          float acc2[4][4];
          #pragma unroll
          for (int i=0;i<4;i++){ acc2[i][0]=acc2[i][1]=acc2[i][2]=acc2[i][3]=0.0f; }
          gfull(sY, w1, cg, rg, acc2);
          float* op = out + ((size_t)b*TT + (size_t)ck*CK + t0)*DD;
          #pragma unroll
          for (int rr=0;rr<4;rr++)
            #pragma unroll
            for (int j=0;j<4;j++){
              int col = cg+64*j;
              op[(size_t)(rg*4+rr)*DD + col] = sX[(rg*4+rr)*260+col] + acc2[rr][j];
            }
        } else {
          int sm = chn-3;
          __hip_bfloat16* hd = B + BOFF_H + ((size_t)(b*6+chn))*CK*DD;
          const float* w1s = W + OFF_W1S + ((size_t)b*2+sm)*DD;
          const float* wsk = W + OFF_WSK + ((size_t)b*2+sm)*DD;
          float p[4];
          #pragma unroll
          for (int rr=0;rr<4;rr++){
            float ps = 0.0f;
            #pragma unroll
            for (int j=0;j<4;j++){
              int col = cg+64*j;
              float h = geluf(acc1[rr][j]);
              hd[(size_t)(t0+rg*4+rr)*DD + col] = __float2bfloat16(h);
              ps += sX[(rg*4+rr)*260+col]*wsk[col] + h*w1s[col];
            }
            p[rr] = ps;
          }
          __hip_bfloat16* pd2 = B + BOFF_P + ((size_t)(b*6+chn))*CK*DD;
          #pragma unroll
          for (int rr=0;rr<4;rr++){
            float f = wsum(p[rr]);                      // all lanes hold row value
            int t = t0 + rg*4 + rr;
            float gs = 2.0f*(256.0f*f - sSc[32 + rg*4+rr]);
            if (cg == 0) W[OFF_GS + ((size_t)b*2+sm)*CK + t] = gs;
            float ge = gs * sSc[16 + rg*4+rr];          // g*eta
            #pragma unroll
            for (int j=0;j<4;j++){
              int col = cg+64*j;
              pd2[(size_t)t*DD + col] =
                __float2bfloat16(ge*w1s[col]*dgeluf(acc1[rr][j]));
            }
          }
        }
      } else {
        // abar = prod_t sigmoid(alpha_t)
        if (tid < 64){
          float v = W[OFF_SALP + (size_t)b*CK + tid];
          #pragma unroll
          for (int off=32; off>0; off>>=1) v *= __shfl_xor(v, off, 64);
          if (tid == 0) W[OFF_ABAR + b] = v;
        }
      }
      __syncthreads();
    }
    bar += 32; bbar(cnt, bar);

    // ================= phase 3: state updates (82 half-tasks/b) ================
    {
      if (tid < 64){
        sEt[tid] = W[OFF_ETA + (size_t)b*CK + tid];
        sSk[tid] = W[OFF_SCK + (size_t)b*CK + tid];
      }
      __syncthreads();
      float ab = W[OFF_ABAR + b];
      const unsigned short* fk = (const unsigned short*)(B + BOFF_F + ((size_t)0*NB+b)*CK*DD);
      float* sT = sMem;      // 32*68 floats used
      int c = tid;
      for (int task=wb; task<82; task+=32){
        if (task < 32){
          // w1[o0..o0+31][c] -= sum_t g[t,o]*eta[t]*h[t,c]
          int mi = task>>3, o0 = (task&7)*32;
          int m = (mi==3)?5:mi;
          const unsigned short* hb = (const unsigned short*)(B + BOFF_H + ((size_t)(b*6+m))*CK*DD);
          const unsigned short* gb = (const unsigned short*)(B + BOFF_GB + ((size_t)(b*4+mi))*CK*DD);
          float* w1 = W + OFF_W1B + ((size_t)b*4+mi)*MSZ;
          float hv[64];
          #pragma unroll
          for (int t=0;t<64;t++) hv[t] = bfu(hb[(size_t)t*DD + c]);
          for (int l=tid; l<2048; l+=256){
            int t=l>>5, oo=l&31;
            sT[oo*68+t] = bfu(gb[(size_t)t*DD + o0+oo]) * sEt[t];
          }
          __syncthreads();
          for (int oo=0; oo<32; oo++){
            float s = 0.0f;
            #pragma unroll
            for (int t4=0; t4<16; t4++){
              float4 g4 = *(const float4*)(sT + oo*68 + t4*4);
              s += g4.x*hv[4*t4] + g4.y*hv[4*t4+1] + g4.z*hv[4*t4+2] + g4.w*hv[4*t4+3];
            }
            size_t idx = (size_t)(o0+oo)*DD + c;
            w1[idx] = ab*w1[idx] - s;
          }
        } else if (task < 80){
          // w2[h0..h0+31][c] -= sum_t P[t,h]*k[t,c]
          int r = task-32, m = r>>3, h0 = (r&7)*32;
          const unsigned short* pd2 = (const unsigned short*)(B + BOFF_P + ((size_t)(b*6+m))*CK*DD);
          float* w2 = W + OFF_W2 + ((size_t)b*6+m)*MSZ;
          float kc[64];
          #pragma unroll
          for (int t=0;t<64;t++) kc[t] = bfu(fk[(size_t)t*DD+c]) * sSk[t];
          for (int l=tid; l<2048; l+=256){
            int t=l>>5, hh=l&31;
            sT[hh*68+t] = bfu(pd2[(size_t)t*DD + h0+hh]);
          }
          __syncthreads();
          for (int hh=0; hh<32; hh++){
            float s = 0.0f;
            #pragma unroll
            for (int t4=0; t4<16; t4++){
              float4 p4 = *(const float4*)(sT + hh*68 + t4*4);
              s += p4.x*kc[4*t4] + p4.y*kc[4*t4+1] + p4.z*kc[4*t4+2] + p4.w*kc[4*t4+3];
            }
            size_t idx = (size_t)(h0+hh)*DD + c;
            w2[idx] = ab*w2[idx] - s;
          }
        } else {
          // small-state updates
          int sm = task-80, m = 3+sm;
          const unsigned short* hb = (const unsigned short*)(B + BOFF_H + ((size_t)(b*6+m))*CK*DD);
          float s1=0.0f, s2=0.0f;
          #pragma unroll
          for (int t=0;t<64;t++){
            float ge = W[OFF_GS + ((size_t)b*2+sm)*CK + t] * sEt[t];
            s1 += ge * bfu(hb[(size_t)t*DD+c]);
            s2 += ge * bfu(fk[(size_t)t*DD+c]) * sSk[t];
          }
          float* w1s = W + OFF_W1S + ((size_t)b*2+sm)*DD;
          float* wskp= W + OFF_WSK + ((size_t)b*2+sm)*DD;
          w1s[c]  = ab*w1s[c]  - s1;
          wskp[c] = ab*wskp[c] - s2;
        }
        __syncthreads();
      }
    }
    bar += 32; bbar(cnt, bar);
  }
}

// ---------------- host ----------------
extern "C" void kernel_launch(void* const* d_in, const int* in_sizes, int n_in,
                              void* d_out, int out_size, void* d_ws, size_t ws_size,
                              hipStream_t stream){
  const float* x = (const float*)d_in[0];
  float* W = (float*)d_ws;
  __hip_bfloat16* B = (__hip_bfloat16*)(W + FTOT);
  float* out = (float*)d_out;

  initk<<<NB*6, 256, 0, stream>>>(W,
      (const float*)d_in[1], (const float*)d_in[2],
      (const float*)d_in[3], (const float*)d_in[4],
      (const float*)d_in[5], (const float*)d_in[6],
      (const float*)d_in[7], (const float*)d_in[8],
      (const float*)d_in[9], (const float*)d_in[10],
      (const float*)d_in[11], (const float*)d_in[12],
      (const float*)d_in[13], (const float*)d_in[14]);

  pers<<<256, 256, 0, stream>>>(x, W, B, out);
}